// Round 5
// baseline (1205.171 us; speedup 1.0000x reference)
//
#include <hip/hip_runtime.h>

// PhysNetCore: N=100k atoms, F=64, R=16, P=1.6M pairs, f32 in/out.
// R5 design (dense kernels rewritten; k_pairs/k_prepw identical to R4):
//  - Block-cooperative dense: block 512 = 8 waves owns one 64-atom group.
//    Wave w computes output features [8w,8w+8) only -> per k-step just 2
//    s_load_dwordx4 of weights (deeply prefetchable), 8 fmac/lane.
//  - ONE shared h-buffer per block (16KB, XOR-swizzled 16B chunks: conflict-
//    minimal b128 reads AND writes), ping-pong pair + 1 barrier per matvec.
//  - Residual state vacc[8] in VGPRs (lane=atom, wave=f-slice).
//  - LDS 36KB/block -> 4 blocks/CU = 32 waves/CU (vs 18% occupancy in R4).

#define NATOMS 100000
#define F 64
#define RDIM 16
#define NPAIRS 1600000
#define AOUT 2
#define NGROUPS 1563   // ceil(NATOMS/64)

__device__ __forceinline__ float sp(float x) {
    // softplus = max(x,0) + log1p(exp(-|x|))
    return fmaxf(x, 0.f) + __logf(1.f + __expf(-fabsf(x)));
}

__device__ __forceinline__ float bcast(float x, int k) {
    return __uint_as_float(__builtin_amdgcn_readlane(__float_as_uint(x), k));
}

// ---- swizzled h-buffer: row a (atom), 64 f32. 16B chunk c stored at c^(a&15).
// reads (lane=a): b128 at chunk k4^(a&15) -> 8 lanes per 4-bank group = minimal.
// writes (owner wave, chunks 2w,2w+1): same distribution = minimal.

// acc[j] += sum_k h[a=lane][k] * wt[k*64 + f0 + j],  j=0..7 (acc pre-set to bias)
__device__ __forceinline__ void mv8(const float* __restrict__ hbuf,
                                    const float* __restrict__ wt,
                                    int lane, int f0, float acc[8]) {
    const int s = lane & 15;
    const float* hrow = hbuf + lane * 64;
#pragma unroll 4
    for (int k4 = 0; k4 < 16; ++k4) {
        const float4 h4 = *(const float4*)(hrow + ((k4 ^ s) << 2));
#pragma unroll
        for (int kk = 0; kk < 4; ++kk) {
            const float hk = (kk == 0) ? h4.x : (kk == 1) ? h4.y : (kk == 2) ? h4.z : h4.w;
            const float* w = wt + (k4 * 4 + kk) * F + f0;      // wave-uniform -> s_load
            const float4 wa = *(const float4*)(w);
            const float4 wb = *(const float4*)(w + 4);
            acc[0] = fmaf(hk, wa.x, acc[0]);
            acc[1] = fmaf(hk, wa.y, acc[1]);
            acc[2] = fmaf(hk, wa.z, acc[2]);
            acc[3] = fmaf(hk, wa.w, acc[3]);
            acc[4] = fmaf(hk, wb.x, acc[4]);
            acc[5] = fmaf(hk, wb.y, acc[5]);
            acc[6] = fmaf(hk, wb.z, acc[6]);
            acc[7] = fmaf(hk, wb.w, acc[7]);
        }
    }
}

__device__ __forceinline__ void hwrite8(float* hbuf, int lane, int f0, const float v[8]) {
    const int s = lane & 15;
    float* row = hbuf + lane * 64;
    const int c0 = (((f0 >> 2) + 0) ^ s) << 2;
    const int c1 = (((f0 >> 2) + 1) ^ s) << 2;
    *(float4*)(row + c0) = make_float4(v[0], v[1], v[2], v[3]);
    *(float4*)(row + c1) = make_float4(v[4], v[5], v[6], v[7]);
}

__device__ __forceinline__ void bias8(const float* __restrict__ b, int f0, float acc[8]) {
    const float4 b0 = *(const float4*)(b + f0);       // uniform -> s_load
    const float4 b1 = *(const float4*)(b + f0 + 4);
    acc[0] = b0.x; acc[1] = b0.y; acc[2] = b0.z; acc[3] = b0.w;
    acc[4] = b1.x; acc[5] = b1.y; acc[6] = b1.z; acc[7] = b1.w;
}

// P0: transpose 13 64x64 weight matrices into ws: Wt[m][k*64+f] = W_m[f*64+k]
__global__ __launch_bounds__(1024) void k_prepw(
    const float* __restrict__ Wi, const float* __restrict__ Wj,
    const float* __restrict__ r1, const float* __restrict__ r2,
    const float* __restrict__ Wv, const float* __restrict__ o1,
    const float* __restrict__ o2, float* __restrict__ Wt)
{
    const int m = blockIdx.x;
    const float* src;
    if      (m == 0) src = Wi;
    else if (m == 1) src = Wj;
    else if (m <  5) src = r1 + (m - 2) * 4096;
    else if (m <  8) src = r2 + (m - 5) * 4096;
    else if (m == 8) src = Wv;
    else if (m < 11) src = o1 + (m - 9) * 4096;
    else             src = o2 + (m - 11) * 4096;
    for (int idx = threadIdx.x; idx < 4096; idx += 1024) {
        const int k = idx >> 6, f = idx & 63;
        Wt[m * 4096 + k * 64 + f] = src[f * 64 + k];
    }
}

// K1: pe = sp(emb); v0 = sp(pe@Wi.T+bi) -> v; Y = sp(pe@Wj.T+bj) -> Y
__global__ __launch_bounds__(512) void k_init(
    const float* __restrict__ emb, const float* __restrict__ Wt,
    const float* __restrict__ bi, const float* __restrict__ bj,
    float* __restrict__ v, float* __restrict__ Y)
{
    __shared__ float hA[64 * 64];
    const int tid = threadIdx.x, lane = tid & 63, wv = tid >> 6;
    const int base = blockIdx.x * 64;
    const int atom = base + lane;
    const bool ok = atom < NATOMS;
    const int f0 = wv * 8;
    // stage pe = sp(emb) into swizzled h (each wave: rows wv, wv+8, ...)
#pragma unroll
    for (int t = 0; t < 8; ++t) {
        const int a = wv + t * 8;
        const int at = base + a < NATOMS ? base + a : NATOMS - 1;
        const float x = sp(emb[(size_t)at * F + lane]);
        hA[a * 64 + ((((lane >> 2) ^ (a & 15)) << 2) | (lane & 3))] = x;
    }
    __syncthreads();
    float acc[8];
    bias8(bi, f0, acc);
    mv8(hA, Wt + 0 * 4096, lane, f0, acc);
    if (ok) {
        float o[8];
#pragma unroll
        for (int j = 0; j < 8; ++j) o[j] = sp(acc[j]);
        *(float4*)(v + (size_t)atom * F + f0)     = make_float4(o[0], o[1], o[2], o[3]);
        *(float4*)(v + (size_t)atom * F + f0 + 4) = make_float4(o[4], o[5], o[6], o[7]);
    }
    bias8(bj, f0, acc);
    mv8(hA, Wt + 1 * 4096, lane, f0, acc);
    if (ok) {
        float o[8];
#pragma unroll
        for (int j = 0; j < 8; ++j) o[j] = sp(acc[j]);
        *(float4*)(Y + (size_t)atom * F + f0)     = make_float4(o[0], o[1], o[2], o[3]);
        *(float4*)(Y + (size_t)atom * F + f0 + 4) = make_float4(o[4], o[5], o[6], o[7]);
    }
}

// K2: per pair p: g[f] = f_ij[p]@Wg[f,:] ; atomicAdd(v[idx_i], Y[idx_j]*g)
__global__ __launch_bounds__(256) void k_pairs(
    const float* __restrict__ fij, const int* __restrict__ pidx,
    const float* __restrict__ Wg, const float* __restrict__ Y,
    float* __restrict__ v)
{
    const int lane = threadIdx.x & 63;
    const int wid = blockIdx.x * 4 + (threadIdx.x >> 6);
    const int nw = gridDim.x * 4;
    float wg[16];
    {
        const float4* s = (const float4*)(Wg + lane * RDIM);
        const float4 x0 = s[0], x1 = s[1], x2 = s[2], x3 = s[3];
        wg[0] = x0.x; wg[1] = x0.y; wg[2]  = x0.z; wg[3]  = x0.w;
        wg[4] = x1.x; wg[5] = x1.y; wg[6]  = x1.z; wg[7]  = x1.w;
        wg[8] = x2.x; wg[9] = x2.y; wg[10] = x2.z; wg[11] = x2.w;
        wg[12] = x3.x; wg[13] = x3.y; wg[14] = x3.z; wg[15] = x3.w;
    }
    for (int p0 = wid * 4; p0 < NPAIRS; p0 += nw * 4) {
        const float fv = fij[p0 * RDIM + lane];
        int ii[4], jj[4];
        float yv[4];
#pragma unroll
        for (int q = 0; q < 4; ++q) {
            ii[q] = pidx[p0 + q];
            jj[q] = pidx[NPAIRS + p0 + q];
        }
#pragma unroll
        for (int q = 0; q < 4; ++q) yv[q] = Y[jj[q] * F + lane];
#pragma unroll
        for (int q = 0; q < 4; ++q) {
            float g = 0.f;
#pragma unroll
            for (int r = 0; r < RDIM; ++r)
                g = fmaf(bcast(fv, q * 16 + r), wg[r], g);
            atomicAdd(v + ii[q] * F + lane, yv[q] * g);
        }
    }
}

// K3 (fused): 3 in-residuals, u = gate*pe + sp(v)@Wv.T + bv (-> uemb),
//             2 out-residuals, pred = x@Wout.T + bout.
__global__ __launch_bounds__(512) void k_res(
    const float* __restrict__ emb, const float* __restrict__ Wt,
    const float* __restrict__ rinb1, const float* __restrict__ rinb2,
    const float* __restrict__ bv, const float* __restrict__ gate,
    const float* __restrict__ routb1, const float* __restrict__ routb2,
    const float* __restrict__ Wout, const float* __restrict__ bout,
    const float* __restrict__ vin, float* __restrict__ uemb,
    float* __restrict__ pred)
{
    __shared__ float hA[64 * 64];
    __shared__ float hB[64 * 64];
    __shared__ float ps[8][64][2];
    const int tid = threadIdx.x, lane = tid & 63, wv = tid >> 6;
    const int base = blockIdx.x * 64;
    const int atom = base + lane;
    const bool ok = atom < NATOMS;
    const int atl = ok ? atom : NATOMS - 1;   // clamped load address
    const int f0 = wv * 8;

    float vacc[8], hv[8], acc[8];
    {
        const float4 t0 = *(const float4*)(vin + (size_t)atl * F + f0);
        const float4 t1 = *(const float4*)(vin + (size_t)atl * F + f0 + 4);
        vacc[0] = t0.x; vacc[1] = t0.y; vacc[2] = t0.z; vacc[3] = t0.w;
        vacc[4] = t1.x; vacc[5] = t1.y; vacc[6] = t1.z; vacc[7] = t1.w;
    }
#pragma unroll
    for (int j = 0; j < 8; ++j) hv[j] = sp(vacc[j]);
    hwrite8(hA, lane, f0, hv);
    __syncthreads();

    // 3 interaction residuals: hA -> hB -> hA (hA ends as sp(vacc))
#pragma unroll 1
    for (int r = 0; r < 3; ++r) {
        bias8(rinb1 + r * F, f0, acc);
        mv8(hA, Wt + (2 + r) * 4096, lane, f0, acc);
#pragma unroll
        for (int j = 0; j < 8; ++j) hv[j] = sp(acc[j]);
        hwrite8(hB, lane, f0, hv);
        __syncthreads();
        bias8(rinb2 + r * F, f0, acc);
        mv8(hB, Wt + (5 + r) * 4096, lane, f0, acc);
#pragma unroll
        for (int j = 0; j < 8; ++j) { vacc[j] += acc[j]; hv[j] = sp(vacc[j]); }
        hwrite8(hA, lane, f0, hv);
        __syncthreads();
    }
    // u = gate*pe + sp(v)@Wv.T + bv
    bias8(bv, f0, acc);
    mv8(hA, Wt + 8 * 4096, lane, f0, acc);
    {
        const float4 e0 = *(const float4*)(emb + (size_t)atl * F + f0);
        const float4 e1 = *(const float4*)(emb + (size_t)atl * F + f0 + 4);
        const float4 g0 = *(const float4*)(gate + f0);
        const float4 g1 = *(const float4*)(gate + f0 + 4);
        vacc[0] = g0.x * sp(e0.x) + acc[0];
        vacc[1] = g0.y * sp(e0.y) + acc[1];
        vacc[2] = g0.z * sp(e0.z) + acc[2];
        vacc[3] = g0.w * sp(e0.w) + acc[3];
        vacc[4] = g1.x * sp(e1.x) + acc[4];
        vacc[5] = g1.y * sp(e1.y) + acc[5];
        vacc[6] = g1.z * sp(e1.z) + acc[6];
        vacc[7] = g1.w * sp(e1.w) + acc[7];
    }
    if (ok) {
        *(float4*)(uemb + (size_t)atom * F + f0)     = make_float4(vacc[0], vacc[1], vacc[2], vacc[3]);
        *(float4*)(uemb + (size_t)atom * F + f0 + 4) = make_float4(vacc[4], vacc[5], vacc[6], vacc[7]);
    }
#pragma unroll
    for (int j = 0; j < 8; ++j) hv[j] = sp(vacc[j]);
    hwrite8(hB, lane, f0, hv);
    __syncthreads();

    // 2 output residuals: hB -> hA -> hB
#pragma unroll 1
    for (int r = 0; r < 2; ++r) {
        bias8(routb1 + r * F, f0, acc);
        mv8(hB, Wt + (9 + r) * 4096, lane, f0, acc);
#pragma unroll
        for (int j = 0; j < 8; ++j) hv[j] = sp(acc[j]);
        hwrite8(hA, lane, f0, hv);
        __syncthreads();
        bias8(routb2 + r * F, f0, acc);
        mv8(hA, Wt + (11 + r) * 4096, lane, f0, acc);
#pragma unroll
        for (int j = 0; j < 8; ++j) { vacc[j] += acc[j]; hv[j] = sp(vacc[j]); }
        if (r == 0) {
            hwrite8(hB, lane, f0, hv);
            __syncthreads();
        }
    }
    // pred = x @ Wout.T + bout : per-wave partial dot over its 8-f slice
    {
        const float4 w00 = *(const float4*)(Wout + f0);
        const float4 w01 = *(const float4*)(Wout + f0 + 4);
        const float4 w10 = *(const float4*)(Wout + F + f0);
        const float4 w11 = *(const float4*)(Wout + F + f0 + 4);
        float p0 = vacc[0] * w00.x + vacc[1] * w00.y + vacc[2] * w00.z + vacc[3] * w00.w
                 + vacc[4] * w01.x + vacc[5] * w01.y + vacc[6] * w01.z + vacc[7] * w01.w;
        float p1 = vacc[0] * w10.x + vacc[1] * w10.y + vacc[2] * w10.z + vacc[3] * w10.w
                 + vacc[4] * w11.x + vacc[5] * w11.y + vacc[6] * w11.z + vacc[7] * w11.w;
        ps[wv][lane][0] = p0;
        ps[wv][lane][1] = p1;
    }
    __syncthreads();
    if (tid < 128) {
        const int a = tid >> 1, c = tid & 1;
        float s = bout[c];
#pragma unroll
        for (int w = 0; w < 8; ++w) s += ps[w][a][c];
        if (base + a < NATOMS) pred[(size_t)(base + a) * AOUT + c] = s;
    }
}

extern "C" void kernel_launch(void* const* d_in, const int* in_sizes, int n_in,
                              void* d_out, int out_size, void* d_ws, size_t ws_size,
                              hipStream_t stream)
{
    const float* emb    = (const float*)d_in[0];
    const float* fij    = (const float*)d_in[1];
    const int*   pidx   = (const int*)d_in[2];
    const float* Wg     = (const float*)d_in[3];
    const float* Wi     = (const float*)d_in[4];
    const float* bi     = (const float*)d_in[5];
    const float* Wj     = (const float*)d_in[6];
    const float* bj     = (const float*)d_in[7];
    const float* Wv     = (const float*)d_in[8];
    const float* bv     = (const float*)d_in[9];
    const float* gate   = (const float*)d_in[10];
    const float* rinW1  = (const float*)d_in[11];
    const float* rinb1  = (const float*)d_in[12];
    const float* rinW2  = (const float*)d_in[13];
    const float* rinb2  = (const float*)d_in[14];
    const float* routW1 = (const float*)d_in[15];
    const float* routb1 = (const float*)d_in[16];
    const float* routW2 = (const float*)d_in[17];
    const float* routb2 = (const float*)d_in[18];
    const float* Wout   = (const float*)d_in[19];
    const float* bout   = (const float*)d_in[20];

    float* pred = (float*)d_out;                    // [N,2]
    float* uemb = (float*)d_out + NATOMS * AOUT;    // [N,64]
    float* v    = uemb;                             // alias: row-disjoint per group

    float* Y  = (float*)d_ws;                       // [N,64]
    float* Wt = Y + (size_t)NATOMS * F;             // 13 * 4096 floats

    k_prepw<<<13, 1024, 0, stream>>>(Wi, Wj, rinW1, rinW2, Wv, routW1, routW2, Wt);
    k_init<<<NGROUPS, 512, 0, stream>>>(emb, Wt, bi, bj, v, Y);
    k_pairs<<<2048, 256, 0, stream>>>(fij, pidx, Wg, Y, v);
    k_res<<<NGROUPS, 512, 0, stream>>>(emb, Wt, rinb1, rinb2, bv, gate,
                                       routb1, routb2, Wout, bout, v, uemb, pred);
}

// Round 7
// 720.414 us; speedup vs baseline: 1.6729x; 1.6729x over previous
//
#include <hip/hip_runtime.h>

// PhysNetCore: N=100k atoms, F=64, R=16, P=1.6M pairs, f32 in/out.
// R7 design:
//  - Dense 64x64 layers via SPLIT-bf16 MFMA: x ~ hi + lo (two bf16), product
//    AhBh + AlBh + AhBl in f32 accum -> ~17-bit effective input mantissa
//    (fixes R6's 0.64 absmax chained-rounding failure at 3x MFMA cost).
//  - One wave per 64-atom group, no barriers. Residual v lives in the 64
//    C/D-slot VGPRs (f32x4[16]); MFMA accumulates residual adds in-place.
//  - Activations h in per-wave LDS as hi/lo bf16-pair rows, HSTR=36 dwords
//    (16B-aligned b128 reads, 2-way-free bank stride).
//  - Weights pre-split+packed once (k_prepw) into BfH/BfL fragments in ws.
//  - k_pairs byte-identical to R5/R6 (A/B isolation).

#define NATOMS 100000
#define F 64
#define RDIM 16
#define NPAIRS 1600000
#define AOUT 2
#define NGROUPS 1563   // ceil(NATOMS/64)
#define WPB 4          // waves per block
#define NBLK 391       // ceil(NGROUPS/WPB)
#define HSTR 36        // dwords per row per (hi|lo) activation buffer
#define WDW (2 * 64 * HSTR)   // per-wave LDS dwords (hi buf + lo buf)

typedef __attribute__((ext_vector_type(8))) short short8;
typedef __attribute__((ext_vector_type(4))) float f32x4;

__device__ __forceinline__ float sp(float x) {
    // softplus = max(x,0) + log1p(exp(-|x|))
    return fmaxf(x, 0.f) + __logf(1.f + __expf(-fabsf(x)));
}

__device__ __forceinline__ float bcast(float x, int k) {
    return __uint_as_float(__builtin_amdgcn_readlane(__float_as_uint(x), k));
}

__device__ __forceinline__ unsigned bf16u(float x) {   // bf16 bits (RNE), low 16
    unsigned d;
    asm("v_cvt_pk_bf16_f32 %0, %1, %2" : "=v"(d) : "v"(x), "v"(x));
    return d & 0xffffu;
}
__device__ __forceinline__ float bf16f(unsigned u) {
    return __uint_as_float(u << 16);
}
// pack two values into hi-dword + lo-dword (split residual)
__device__ __forceinline__ void packsplit2(float x, float y, unsigned* dh, unsigned* dl) {
    const unsigned hx = bf16u(x), hy = bf16u(y);
    *dh = hx | (hy << 16);
    *dl = bf16u(x - bf16f(hx)) | (bf16u(y - bf16f(hy)) << 16);
}
__device__ __forceinline__ void split1(float x, unsigned short* h, unsigned short* l) {
    const unsigned hx = bf16u(x);
    *h = (unsigned short)hx;
    *l = (unsigned short)bf16u(x - bf16f(hx));
}
__device__ __forceinline__ short8 mkfrag(unsigned d0, unsigned d1, unsigned d2, unsigned d3) {
    union { unsigned u[4]; short8 s; } x;
    x.u[0] = d0; x.u[1] = d1; x.u[2] = d2; x.u[3] = d3;
    return x.s;
}

// acc += A*B with split precision. A from LDS hi/lo bufs, B from BfH/BfL.
// Slot convention (same bijection for A and B, so any k-permutation cancels):
// 16x16x32 frag: lane = {idx c=lane&15, chunk g=lane>>4}, k = 32ks+8g+2t,2t+1.
__device__ __forceinline__ void mm64s(const unsigned* hH, const unsigned* hL,
                                      const uint4* __restrict__ BH,
                                      const uint4* __restrict__ BL,
                                      int lane, f32x4 acc[16]) {
    const int c = lane & 15, g = lane >> 4;
#pragma unroll
    for (int ks = 0; ks < 2; ++ks) {
        short8 Ah[4], Al[4];
#pragma unroll
        for (int mt = 0; mt < 4; ++mt) {
            const int bi = HSTR * (c + 16 * mt) + 16 * ks + 4 * g;  // 16B aligned
            Ah[mt] = mkfrag(hH[bi], hH[bi + 1], hH[bi + 2], hH[bi + 3]);
            Al[mt] = mkfrag(hL[bi], hL[bi + 1], hL[bi + 2], hL[bi + 3]);
        }
#pragma unroll
        for (int nt = 0; nt < 4; ++nt) {
            const uint4 bh = BH[(ks * 4 + nt) * 64 + lane];
            const uint4 bl = BL[(ks * 4 + nt) * 64 + lane];
            const short8 Bh = mkfrag(bh.x, bh.y, bh.z, bh.w);
            const short8 Bl = mkfrag(bl.x, bl.y, bl.z, bl.w);
#pragma unroll
            for (int mt = 0; mt < 4; ++mt) {
                f32x4 a = acc[mt * 4 + nt];
                a = __builtin_amdgcn_mfma_f32_16x16x32_bf16(Ah[mt], Bh, a, 0, 0, 0);
                a = __builtin_amdgcn_mfma_f32_16x16x32_bf16(Al[mt], Bh, a, 0, 0, 0);
                a = __builtin_amdgcn_mfma_f32_16x16x32_bf16(Ah[mt], Bl, a, 0, 0, 0);
                acc[mt * 4 + nt] = a;
            }
        }
    }
}

// h' = sp(W*h + b) -> hi/lo bufs (C/D layout: row=16mt+4g+r, col=16nt+c)
__device__ __forceinline__ void layer_sp(unsigned* hH, unsigned* hL,
                                         const uint4* __restrict__ BH,
                                         const uint4* __restrict__ BL,
                                         const float* __restrict__ bias, int lane) {
    const int c = lane & 15, g = lane >> 4;
    float bz[4];
#pragma unroll
    for (int nt = 0; nt < 4; ++nt) bz[nt] = bias[16 * nt + c];
    f32x4 acc[16];
#pragma unroll
    for (int i = 0; i < 16; ++i) {
        f32x4 z; z[0] = z[1] = z[2] = z[3] = bz[i & 3]; acc[i] = z;
    }
    mm64s(hH, hL, BH, BL, lane, acc);
    unsigned short* sH = (unsigned short*)hH;
    unsigned short* sL = (unsigned short*)hL;
#pragma unroll
    for (int mt = 0; mt < 4; ++mt)
#pragma unroll
        for (int nt = 0; nt < 4; ++nt)
#pragma unroll
            for (int r = 0; r < 4; ++r) {
                const int a = 16 * mt + 4 * g + r;
                const int col = 16 * nt + c;
                split1(sp(acc[mt * 4 + nt][r]),
                       sH + a * 2 * HSTR + col, sL + a * 2 * HSTR + col);
            }
}

// v += W*h + b (in the v registers); optionally write sp(v) to hi/lo bufs
__device__ __forceinline__ void layer_res(f32x4 vreg[16], unsigned* hH, unsigned* hL,
                                          const uint4* __restrict__ BH,
                                          const uint4* __restrict__ BL,
                                          const float* __restrict__ bias,
                                          int lane, bool writeH) {
    const int c = lane & 15, g = lane >> 4;
#pragma unroll
    for (int nt = 0; nt < 4; ++nt) {
        const float b = bias[16 * nt + c];
#pragma unroll
        for (int mt = 0; mt < 4; ++mt) {
            vreg[mt * 4 + nt][0] += b; vreg[mt * 4 + nt][1] += b;
            vreg[mt * 4 + nt][2] += b; vreg[mt * 4 + nt][3] += b;
        }
    }
    mm64s(hH, hL, BH, BL, lane, vreg);
    if (writeH) {
        unsigned short* sH = (unsigned short*)hH;
        unsigned short* sL = (unsigned short*)hL;
#pragma unroll
        for (int mt = 0; mt < 4; ++mt)
#pragma unroll
            for (int nt = 0; nt < 4; ++nt)
#pragma unroll
                for (int r = 0; r < 4; ++r) {
                    const int a = 16 * mt + 4 * g + r;
                    const int col = 16 * nt + c;
                    split1(sp(vreg[mt * 4 + nt][r]),
                           sH + a * 2 * HSTR + col, sL + a * 2 * HSTR + col);
                }
    }
}

// P0: split-pack 13 weight matrices into bf16 hi/lo B-fragments.
__global__ __launch_bounds__(512) void k_prepw(
    const float* __restrict__ Wi, const float* __restrict__ Wj,
    const float* __restrict__ r1, const float* __restrict__ r2,
    const float* __restrict__ Wv, const float* __restrict__ o1,
    const float* __restrict__ o2, uint4* __restrict__ BfH, uint4* __restrict__ BfL)
{
    const int m = blockIdx.x;
    const float* src;
    if      (m == 0) src = Wi;
    else if (m == 1) src = Wj;
    else if (m <  5) src = r1 + (m - 2) * 4096;
    else if (m <  8) src = r2 + (m - 5) * 4096;
    else if (m == 8) src = Wv;
    else if (m < 11) src = o1 + (m - 9) * 4096;
    else             src = o2 + (m - 11) * 4096;
    const int tid = threadIdx.x;
    const int lane = tid & 63, nt = (tid >> 6) & 3, ks = tid >> 8;
    const int c = lane & 15, g = lane >> 4;
    const int fr = 16 * nt + c;          // output feature (B col) = W row
    const int k0 = 32 * ks + 8 * g;      // k (B row) = W col
    unsigned dh[4], dl[4];
#pragma unroll
    for (int t = 0; t < 4; ++t)
        packsplit2(src[fr * F + k0 + 2 * t], src[fr * F + k0 + 2 * t + 1],
                   &dh[t], &dl[t]);
    const int idx = m * 512 + (ks * 4 + nt) * 64 + lane;
    BfH[idx] = make_uint4(dh[0], dh[1], dh[2], dh[3]);
    BfL[idx] = make_uint4(dl[0], dl[1], dl[2], dl[3]);
}

// K1: pe = sp(emb); v0 = sp(pe@Wi.T+bi) -> v ; Y = sp(pe@Wj.T+bj) -> Y
__global__ __launch_bounds__(256) void k_init(
    const float* __restrict__ emb,
    const uint4* __restrict__ BfH, const uint4* __restrict__ BfL,
    const float* __restrict__ bi, const float* __restrict__ bj,
    float* __restrict__ v, float* __restrict__ Y)
{
    extern __shared__ unsigned smu[];
    const int lane = threadIdx.x & 63, wv = threadIdx.x >> 6;
    const int grp = blockIdx.x * WPB + wv;
    if (grp >= NGROUPS) return;
    const int base = grp * 64;
    unsigned* hH = smu + wv * WDW;
    unsigned* hL = hH + 64 * HSTR;
    const int c = lane & 15, g = lane >> 4;
#pragma unroll 4
    for (int t = 0; t < 16; ++t) {
        const int a = 4 * t + g;
        const int at0 = base + a;
        const int at = at0 < NATOMS ? at0 : NATOMS - 1;
        const float4 x = *(const float4*)(emb + (size_t)at * F + 4 * c);
        packsplit2(sp(x.x), sp(x.y), &hH[a * HSTR + 2 * c], &hL[a * HSTR + 2 * c]);
        packsplit2(sp(x.z), sp(x.w), &hH[a * HSTR + 2 * c + 1], &hL[a * HSTR + 2 * c + 1]);
    }
#pragma unroll 1
    for (int m = 0; m < 2; ++m) {
        const float* bias = m == 0 ? bi : bj;
        float* out = m == 0 ? v : Y;
        float bz[4];
#pragma unroll
        for (int nt = 0; nt < 4; ++nt) bz[nt] = bias[16 * nt + c];
        f32x4 acc[16];
#pragma unroll
        for (int i = 0; i < 16; ++i) {
            f32x4 z; z[0] = z[1] = z[2] = z[3] = bz[i & 3]; acc[i] = z;
        }
        mm64s(hH, hL, BfH + m * 512, BfL + m * 512, lane, acc);
#pragma unroll
        for (int mt = 0; mt < 4; ++mt)
#pragma unroll
            for (int nt = 0; nt < 4; ++nt)
#pragma unroll
                for (int r = 0; r < 4; ++r) {
                    const int at = base + 16 * mt + 4 * g + r;
                    if (at < NATOMS)
                        out[(size_t)at * F + 16 * nt + c] = sp(acc[mt * 4 + nt][r]);
                }
    }
}

// K2: per pair p: g[f] = f_ij[p]@Wg[f,:] ; atomicAdd(v[idx_i], Y[idx_j]*g)
__global__ __launch_bounds__(256) void k_pairs(
    const float* __restrict__ fij, const int* __restrict__ pidx,
    const float* __restrict__ Wg, const float* __restrict__ Y,
    float* __restrict__ v)
{
    const int lane = threadIdx.x & 63;
    const int wid = blockIdx.x * 4 + (threadIdx.x >> 6);
    const int nw = gridDim.x * 4;
    float wg[16];
    {
        const float4* s = (const float4*)(Wg + lane * RDIM);
        const float4 x0 = s[0], x1 = s[1], x2 = s[2], x3 = s[3];
        wg[0] = x0.x; wg[1] = x0.y; wg[2]  = x0.z; wg[3]  = x0.w;
        wg[4] = x1.x; wg[5] = x1.y; wg[6]  = x1.z; wg[7]  = x1.w;
        wg[8] = x2.x; wg[9] = x2.y; wg[10] = x2.z; wg[11] = x2.w;
        wg[12] = x3.x; wg[13] = x3.y; wg[14] = x3.z; wg[15] = x3.w;
    }
    for (int p0 = wid * 4; p0 < NPAIRS; p0 += nw * 4) {
        const float fv = fij[p0 * RDIM + lane];
        int ii[4], jj[4];
        float yv[4];
#pragma unroll
        for (int q = 0; q < 4; ++q) {
            ii[q] = pidx[p0 + q];
            jj[q] = pidx[NPAIRS + p0 + q];
        }
#pragma unroll
        for (int q = 0; q < 4; ++q) yv[q] = Y[jj[q] * F + lane];
#pragma unroll
        for (int q = 0; q < 4; ++q) {
            float gq = 0.f;
#pragma unroll
            for (int r = 0; r < RDIM; ++r)
                gq = fmaf(bcast(fv, q * 16 + r), wg[r], gq);
            atomicAdd(v + ii[q] * F + lane, yv[q] * gq);
        }
    }
}

// K3 (fused): 3 in-residuals, u = gate*pe + sp(v)@Wv.T+bv (-> uemb),
//             2 out-residuals, pred = x@Wout.T + bout.  One wave per group.
__global__ __launch_bounds__(256) void k_res(
    const float* __restrict__ emb,
    const uint4* __restrict__ BfH, const uint4* __restrict__ BfL,
    const float* __restrict__ rinb1, const float* __restrict__ rinb2,
    const float* __restrict__ bv, const float* __restrict__ gate,
    const float* __restrict__ routb1, const float* __restrict__ routb2,
    const float* __restrict__ Wout, const float* __restrict__ bout,
    const float* vin, float* uemb, float* __restrict__ pred)   // vin aliases uemb
{
    extern __shared__ unsigned smu[];
    const int lane = threadIdx.x & 63, wv = threadIdx.x >> 6;
    const int grp = blockIdx.x * WPB + wv;
    if (grp >= NGROUPS) return;
    const int base = grp * 64;
    unsigned* hH = smu + wv * WDW;
    unsigned* hL = hH + 64 * HSTR;
    const int c = lane & 15, g = lane >> 4;

    // stage hi/lo activation bufs (coalesced float4 reads of vin)
#pragma unroll 4
    for (int t = 0; t < 16; ++t) {
        const int a = 4 * t + g;
        const int at0 = base + a;
        const int at = at0 < NATOMS ? at0 : NATOMS - 1;
        const float4 x = *(const float4*)(vin + (size_t)at * F + 4 * c);
        packsplit2(sp(x.x), sp(x.y), &hH[a * HSTR + 2 * c], &hL[a * HSTR + 2 * c]);
        packsplit2(sp(x.z), sp(x.w), &hH[a * HSTR + 2 * c + 1], &hL[a * HSTR + 2 * c + 1]);
    }
    // v residual state -> registers, C/D slot layout
    f32x4 vreg[16];
#pragma unroll
    for (int mt = 0; mt < 4; ++mt)
#pragma unroll
        for (int nt = 0; nt < 4; ++nt)
#pragma unroll
            for (int r = 0; r < 4; ++r) {
                const int at0 = base + 16 * mt + 4 * g + r;
                const int at = at0 < NATOMS ? at0 : NATOMS - 1;
                vreg[mt * 4 + nt][r] = vin[(size_t)at * F + 16 * nt + c];
            }

    // 3 interaction residuals
#pragma unroll 1
    for (int r = 0; r < 3; ++r) {
        layer_sp(hH, hL, BfH + (2 + r) * 512, BfL + (2 + r) * 512,
                 rinb1 + r * F, lane);
        layer_res(vreg, hH, hL, BfH + (5 + r) * 512, BfL + (5 + r) * 512,
                  rinb2 + r * F, lane, true);
    }

    // u = gate*pe + sp(v)@Wv.T + bv  (acc init = bv + gate*sp(emb))
    {
        f32x4 acc[16];
#pragma unroll
        for (int nt = 0; nt < 4; ++nt) {
            const float b = bv[16 * nt + c];
            const float gg = gate[16 * nt + c];
#pragma unroll
            for (int mt = 0; mt < 4; ++mt) {
                f32x4 z;
#pragma unroll
                for (int r = 0; r < 4; ++r) {
                    const int at0 = base + 16 * mt + 4 * g + r;
                    const int at = at0 < NATOMS ? at0 : NATOMS - 1;
                    z[r] = b + gg * sp(emb[(size_t)at * F + 16 * nt + c]);
                }
                acc[mt * 4 + nt] = z;
            }
        }
        mm64s(hH, hL, BfH + 8 * 512, BfL + 8 * 512, lane, acc);
        unsigned short* sH = (unsigned short*)hH;
        unsigned short* sL = (unsigned short*)hL;
#pragma unroll
        for (int mt = 0; mt < 4; ++mt)
#pragma unroll
            for (int nt = 0; nt < 4; ++nt)
#pragma unroll
                for (int r = 0; r < 4; ++r) {
                    const int a = 16 * mt + 4 * g + r;
                    const int at = base + a;
                    const int col = 16 * nt + c;
                    const float un = acc[mt * 4 + nt][r];
                    if (at < NATOMS) uemb[(size_t)at * F + col] = un;
                    vreg[mt * 4 + nt][r] = un;
                    split1(sp(un), sH + a * 2 * HSTR + col, sL + a * 2 * HSTR + col);
                }
    }

    // 2 output residuals
#pragma unroll 1
    for (int r = 0; r < 2; ++r) {
        layer_sp(hH, hL, BfH + (9 + r) * 512, BfL + (9 + r) * 512,
                 routb1 + r * F, lane);
        layer_res(vreg, hH, hL, BfH + (11 + r) * 512, BfL + (11 + r) * 512,
                  routb2 + r * F, lane, r == 0);
    }

    // pred = x @ Wout.T + bout ; butterfly-reduce over the 16-lane c group
    {
        float w0[4], w1[4];
#pragma unroll
        for (int nt = 0; nt < 4; ++nt) {
            w0[nt] = Wout[16 * nt + c];
            w1[nt] = Wout[F + 16 * nt + c];
        }
        float p0[16], p1[16];
#pragma unroll
        for (int mt = 0; mt < 4; ++mt)
#pragma unroll
            for (int r = 0; r < 4; ++r) {
                float s0 = 0.f, s1 = 0.f;
#pragma unroll
                for (int nt = 0; nt < 4; ++nt) {
                    s0 = fmaf(vreg[mt * 4 + nt][r], w0[nt], s0);
                    s1 = fmaf(vreg[mt * 4 + nt][r], w1[nt], s1);
                }
                p0[mt * 4 + r] = s0;
                p1[mt * 4 + r] = s1;
            }
#pragma unroll
        for (int i = 0; i < 16; ++i) {
#pragma unroll
            for (int off = 1; off < 16; off <<= 1) {
                p0[i] += __shfl_xor(p0[i], off, 64);
                p1[i] += __shfl_xor(p1[i], off, 64);
            }
        }
        if (c == 0) {
            const float b0 = bout[0], b1 = bout[1];
#pragma unroll
            for (int mt = 0; mt < 4; ++mt)
#pragma unroll
                for (int r = 0; r < 4; ++r) {
                    const int at = base + 16 * mt + 4 * g + r;
                    if (at < NATOMS) {
                        pred[(size_t)at * AOUT + 0] = p0[mt * 4 + r] + b0;
                        pred[(size_t)at * AOUT + 1] = p1[mt * 4 + r] + b1;
                    }
                }
        }
    }
}

extern "C" void kernel_launch(void* const* d_in, const int* in_sizes, int n_in,
                              void* d_out, int out_size, void* d_ws, size_t ws_size,
                              hipStream_t stream)
{
    const float* emb    = (const float*)d_in[0];
    const float* fij    = (const float*)d_in[1];
    const int*   pidx   = (const int*)d_in[2];
    const float* Wg     = (const float*)d_in[3];
    const float* Wi     = (const float*)d_in[4];
    const float* bi     = (const float*)d_in[5];
    const float* Wj     = (const float*)d_in[6];
    const float* bj     = (const float*)d_in[7];
    const float* Wv     = (const float*)d_in[8];
    const float* bv     = (const float*)d_in[9];
    const float* gate   = (const float*)d_in[10];
    const float* rinW1  = (const float*)d_in[11];
    const float* rinb1  = (const float*)d_in[12];
    const float* rinW2  = (const float*)d_in[13];
    const float* rinb2  = (const float*)d_in[14];
    const float* routW1 = (const float*)d_in[15];
    const float* routb1 = (const float*)d_in[16];
    const float* routW2 = (const float*)d_in[17];
    const float* routb2 = (const float*)d_in[18];
    const float* Wout   = (const float*)d_in[19];
    const float* bout   = (const float*)d_in[20];

    float* pred = (float*)d_out;                    // [N,2]
    float* uemb = (float*)d_out + NATOMS * AOUT;    // [N,64]
    float* v    = uemb;                             // alias: row-disjoint per group

    float* Y   = (float*)d_ws;                                      // [N,64] f32
    uint4* BfH = (uint4*)((char*)d_ws + (size_t)NATOMS * F * 4);    // 13*512 uint4
    uint4* BfL = BfH + 13 * 512;

    const int lds = WPB * WDW * 4;   // 73728 B
    (void)hipFuncSetAttribute((const void*)k_init,
                              hipFuncAttributeMaxDynamicSharedMemorySize, lds);
    (void)hipFuncSetAttribute((const void*)k_res,
                              hipFuncAttributeMaxDynamicSharedMemorySize, lds);

    k_prepw<<<13, 512, 0, stream>>>(Wi, Wj, rinW1, rinW2, Wv, routW1, routW2, BfH, BfL);
    k_init<<<NBLK, 256, lds, stream>>>(emb, BfH, BfL, bi, bj, v, Y);
    k_pairs<<<2048, 256, 0, stream>>>(fij, pidx, Wg, Y, v);
    k_res<<<NBLK, 256, lds, stream>>>(emb, BfH, BfL, rinb1, rinb2, bv, gate,
                                      routb1, routb2, Wout, bout, v, uemb, pred);
}